// Round 1
// baseline (1607.154 us; speedup 1.0000x reference)
//
#include <hip/hip_runtime.h>

// ---------------------------------------------------------------------------
// Slot Attention forward, MI355X (gfx950).
// Sizes: B=32, N=4096, DIN=768, D=256, S=8, ITERS=3, SCALE=1/16, EPS=1e-8
// Big GEMMs in bf16 MFMA (16x16x32), slot-side math in fp32.
// ---------------------------------------------------------------------------

typedef __bf16 bf16_t;
typedef __bf16 bf16x8 __attribute__((ext_vector_type(8)));
typedef float f32x4 __attribute__((ext_vector_type(4)));
typedef unsigned short u16x8 __attribute__((ext_vector_type(8)));
typedef unsigned short u16x4 __attribute__((ext_vector_type(4)));

#define B_ 32
#define N_ 4096
#define DIN_ 768
#define D_ 256
#define S_ 8
#define SCALE_ 0.0625f

// fp32 -> bf16 round-to-nearest-even (bit trick; avoids scalar __bf16 math)
__device__ __forceinline__ unsigned short f2b(float f) {
  unsigned u = __float_as_uint(f);
  u = (u + 0x7fffu + ((u >> 16) & 1u)) >> 16;
  return (unsigned short)u;
}
__device__ __forceinline__ float b2f(unsigned short h) {
  return __uint_as_float(((unsigned)h) << 16);
}

__device__ __forceinline__ f32x4 mfma16(bf16x8 a, bf16x8 b, f32x4 c) {
  return __builtin_amdgcn_mfma_f32_16x16x32_bf16(a, b, c, 0, 0, 0);
}

// ---------------------------------------------------------------------------
// Weight prep kernels (run every call; ws is re-poisoned each launch)
// ---------------------------------------------------------------------------
__global__ void k_prep_w1t(const float* __restrict__ w, unsigned short* __restrict__ o) {
  int idx = blockIdx.x * 256 + threadIdx.x;            // < 768*768
  int n = idx / 768, k = idx - n * 768;
  o[idx] = f2b(w[k * 768 + n]);                        // [n][k] bf16
}
__global__ void k_prep_w2t(const float* __restrict__ w, unsigned short* __restrict__ o) {
  int idx = blockIdx.x * 256 + threadIdx.x;            // < 256*768
  int n = idx / 768, k = idx - n * 768;
  o[idx] = f2b(w[k * 256 + n]);                        // [n=256][k=768]
}
__global__ void k_prep_wkv(const float* __restrict__ wk, const float* __restrict__ wv,
                           unsigned short* __restrict__ o) {
  int idx = blockIdx.x * 256 + threadIdx.x;            // < 512*256
  o[idx] = f2b(idx < 65536 ? wk[idx] : wv[idx - 65536]);  // rows 0..255 wk, 256..511 wv
}
__global__ void k_prep_wqt(const float* __restrict__ w, float* __restrict__ o) {
  int idx = blockIdx.x * 256 + threadIdx.x;            // < 256*256
  int k = idx >> 8, n = idx & 255;
  o[idx] = w[n * 256 + k];                             // [k][n] f32
}
__global__ void k_prep_grut(const float* __restrict__ wih, const float* __restrict__ whh,
                            float* __restrict__ oih, float* __restrict__ ohh) {
  int idx = blockIdx.x * 256 + threadIdx.x;            // < 256*768
  int k = idx / 768, n = idx - k * 768;
  oih[idx] = wih[n * 256 + k];                         // [k=256][n=768]
  ohh[idx] = whh[n * 256 + k];
}
__global__ void k_init_slots(const float* __restrict__ si, float* __restrict__ s) {
  int idx = blockIdx.x * 256 + threadIdx.x;            // < 65536
  s[idx] = si[idx & 2047];                             // broadcast [1,S,D] over B
}

// ---------------------------------------------------------------------------
// LN(DIN=768) + bf16 cast: inputs [131072][768] f32 -> h0 bf16
// one wave per row, 4 rows/block
// ---------------------------------------------------------------------------
__global__ __launch_bounds__(256) void k_h0(const float* __restrict__ x,
                                            const float* __restrict__ g,
                                            const float* __restrict__ b,
                                            unsigned short* __restrict__ out) {
  int row = blockIdx.x * 4 + (threadIdx.x >> 6);
  int lane = threadIdx.x & 63;
  const float* xr = x + (size_t)row * 768;
  float4 v[3];
  float s = 0.f, sq = 0.f;
#pragma unroll
  for (int q = 0; q < 3; q++) {
    v[q] = *(const float4*)(xr + q * 256 + lane * 4);
    s  += v[q].x + v[q].y + v[q].z + v[q].w;
    sq += v[q].x * v[q].x + v[q].y * v[q].y + v[q].z * v[q].z + v[q].w * v[q].w;
  }
#pragma unroll
  for (int m = 1; m < 64; m <<= 1) { s += __shfl_xor(s, m); sq += __shfl_xor(sq, m); }
  float mean = s * (1.f / 768.f);
  float rstd = rsqrtf(sq * (1.f / 768.f) - mean * mean + 1e-5f);
  unsigned short* orow = out + (size_t)row * 768;
#pragma unroll
  for (int q = 0; q < 3; q++) {
    float4 gv = *(const float4*)(g + q * 256 + lane * 4);
    float4 bv = *(const float4*)(b + q * 256 + lane * 4);
    u16x4 o;
    o[0] = f2b((v[q].x - mean) * rstd * gv.x + bv.x);
    o[1] = f2b((v[q].y - mean) * rstd * gv.y + bv.y);
    o[2] = f2b((v[q].z - mean) * rstd * gv.z + bv.z);
    o[3] = f2b((v[q].w - mean) * rstd * gv.w + bv.w);
    *(u16x4*)(orow + q * 256 + lane * 4) = o;
  }
}

// ---------------------------------------------------------------------------
// LN(D=256) on bf16 h2 -> feats bf16. one wave per row, 4 rows/block
// ---------------------------------------------------------------------------
__global__ __launch_bounds__(256) void k_ln2(const unsigned short* __restrict__ h2,
                                             const float* __restrict__ g,
                                             const float* __restrict__ b,
                                             unsigned short* __restrict__ out) {
  int row = blockIdx.x * 4 + (threadIdx.x >> 6);
  int lane = threadIdx.x & 63;
  u16x4 hv = *(const u16x4*)(h2 + (size_t)row * 256 + lane * 4);
  float x0 = b2f(hv[0]), x1 = b2f(hv[1]), x2 = b2f(hv[2]), x3 = b2f(hv[3]);
  float s = x0 + x1 + x2 + x3;
  float sq = x0 * x0 + x1 * x1 + x2 * x2 + x3 * x3;
#pragma unroll
  for (int m = 1; m < 64; m <<= 1) { s += __shfl_xor(s, m); sq += __shfl_xor(sq, m); }
  float mean = s * (1.f / 256.f);
  float rstd = rsqrtf(sq * (1.f / 256.f) - mean * mean + 1e-5f);
  float4 gv = *(const float4*)(g + lane * 4);
  float4 bv = *(const float4*)(b + lane * 4);
  u16x4 o;
  o[0] = f2b((x0 - mean) * rstd * gv.x + bv.x);
  o[1] = f2b((x1 - mean) * rstd * gv.y + bv.y);
  o[2] = f2b((x2 - mean) * rstd * gv.z + bv.z);
  o[3] = f2b((x3 - mean) * rstd * gv.w + bv.w);
  *(u16x4*)(out + (size_t)row * 256 + lane * 4) = o;
}

// ---------------------------------------------------------------------------
// bf16 MFMA GEMM: C[M][N] = A[M][K] * Bm[N][K]^T  (both K-contiguous)
// 128x128 tile, 4 waves (2x2 of 64x64), BK=32, LDS padded stride 56.
// MODE 0: relu(x+bias); MODE 1: x+bias; MODE 2: x.  C stored bf16.
// Fragment layouts (verified, learn_hip m89/m91):
//   A/B operand: lane holds [m|n = lane&15][k = (lane>>4)*8 + j]
//   C/D: col = lane&15, row = (lane>>4)*4 + reg
// ---------------------------------------------------------------------------
template <int MODE>
__global__ __launch_bounds__(256) void k_gemm(const unsigned short* __restrict__ A,
                                              const unsigned short* __restrict__ Bm,
                                              const float* __restrict__ bias,
                                              unsigned short* __restrict__ C,
                                              int M, int N, int K) {
  constexpr int LDK = 56;  // padded k-stride (elements): 112B rows, 16B aligned, 2-way banks
  __shared__ __attribute__((aligned(16))) unsigned short lA[128 * LDK];
  __shared__ __attribute__((aligned(16))) unsigned short lB[128 * LDK];
  const int tid = threadIdx.x;
  const int lane = tid & 63, wave = tid >> 6;
  const int m0 = blockIdx.x * 128, n0 = blockIdx.y * 128;
  const int wm = (wave >> 1) * 64, wn = (wave & 1) * 64;
  // staging: thread covers 16 elements (32B): row sr, element offset sh
  const int sr = tid >> 1;
  const int sh = (tid & 1) * 16;
  const unsigned short* pA = A + (size_t)(m0 + sr) * K + sh;
  const unsigned short* pB = Bm + (size_t)(n0 + sr) * K + sh;
  unsigned short* sA = &lA[sr * LDK + sh];
  unsigned short* sB = &lB[sr * LDK + sh];
  const int fr = lane & 15, fq = lane >> 4;

  f32x4 acc[4][4] = {};
  for (int kt = 0; kt < K; kt += 32) {
    uint4 a0 = *(const uint4*)(pA + kt);
    uint4 a1 = *(const uint4*)(pA + kt + 8);
    uint4 b0 = *(const uint4*)(pB + kt);
    uint4 b1 = *(const uint4*)(pB + kt + 8);
    __syncthreads();  // previous iter's LDS reads done
    *(uint4*)sA = a0; *(uint4*)(sA + 8) = a1;
    *(uint4*)sB = b0; *(uint4*)(sB + 8) = b1;
    __syncthreads();
    bf16x8 af[4], bfr[4];
#pragma unroll
    for (int i = 0; i < 4; i++)
      af[i] = __builtin_bit_cast(bf16x8, *(const u16x8*)&lA[(wm + i * 16 + fr) * LDK + fq * 8]);
#pragma unroll
    for (int j = 0; j < 4; j++)
      bfr[j] = __builtin_bit_cast(bf16x8, *(const u16x8*)&lB[(wn + j * 16 + fr) * LDK + fq * 8]);
#pragma unroll
    for (int i = 0; i < 4; i++)
#pragma unroll
      for (int j = 0; j < 4; j++)
        acc[i][j] = mfma16(af[i], bfr[j], acc[i][j]);
  }
#pragma unroll
  for (int i = 0; i < 4; i++)
#pragma unroll
    for (int j = 0; j < 4; j++) {
      int col = n0 + wn + j * 16 + fr;
      float bv = (MODE == 2) ? 0.f : bias[col];
#pragma unroll
      for (int r = 0; r < 4; r++) {
        int row = m0 + wm + i * 16 + fq * 4 + r;
        float v = acc[i][j][r] + bv;
        if (MODE == 0) v = fmaxf(v, 0.f);
        C[(size_t)row * N + col] = f2b(v);
      }
    }
}

// ---------------------------------------------------------------------------
// q = LN(slots) @ wq^T, pre-scaled by SCALE. one block per (b,s) row.
// ---------------------------------------------------------------------------
__global__ __launch_bounds__(256) void k_q(const float* __restrict__ slots,
                                           const float* __restrict__ ng,
                                           const float* __restrict__ nb,
                                           const float* __restrict__ wqT,  // [k][n]
                                           float* __restrict__ qout) {
  __shared__ float ln[256];
  __shared__ float red[8];
  int row = blockIdx.x, tid = threadIdx.x;
  float x = slots[row * 256 + tid];
  float s = x, sq = x * x;
#pragma unroll
  for (int m = 1; m < 64; m <<= 1) { s += __shfl_xor(s, m); sq += __shfl_xor(sq, m); }
  if ((tid & 63) == 0) { red[tid >> 6] = s; red[4 + (tid >> 6)] = sq; }
  __syncthreads();
  s = red[0] + red[1] + red[2] + red[3];
  sq = red[4] + red[5] + red[6] + red[7];
  float mean = s * (1.f / 256.f);
  float rstd = rsqrtf(sq * (1.f / 256.f) - mean * mean + 1e-5f);
  ln[tid] = (x - mean) * rstd * ng[tid] + nb[tid];
  __syncthreads();
  float acc = 0.f;
  for (int k = 0; k < 256; k++) acc += ln[k] * wqT[k * 256 + tid];
  qout[row * 256 + tid] = acc * SCALE_;
}

// ---------------------------------------------------------------------------
// Attention: dots = q.kv_keys (softmax over S per t, +EPS), accumulate
// numerator [S][D] and denominator [S] partials per (b, chunk, wave).
// Each wave: 2 t's at a time via half-wave split; 64 t per wave; 256 t/block.
// ---------------------------------------------------------------------------
__global__ __launch_bounds__(256) void k_attn(const float* __restrict__ q,        // [B][S][256] pre-scaled
                                              const unsigned short* __restrict__ kv, // [B*N][512]
                                              float* __restrict__ nump,           // [B][16][4][S][256]
                                              float* __restrict__ denp) {         // [B][16][4][S]
  int b = blockIdx.y, chunk = blockIdx.x;
  int tid = threadIdx.x, lane = tid & 63, wave = tid >> 6;
  int sub = lane & 31, half = lane >> 5;
  const float* qb = q + b * (S_ * 256);
  float qr[8][8];
#pragma unroll
  for (int s = 0; s < 8; s++) {
    float4 t0 = *(const float4*)(qb + s * 256 + sub * 8);
    float4 t1 = *(const float4*)(qb + s * 256 + sub * 8 + 4);
    qr[s][0] = t0.x; qr[s][1] = t0.y; qr[s][2] = t0.z; qr[s][3] = t0.w;
    qr[s][4] = t1.x; qr[s][5] = t1.y; qr[s][6] = t1.z; qr[s][7] = t1.w;
  }
  float acc[8][8] = {};
  float den[8] = {};
  int t_begin = chunk * 256 + wave * 64;
  for (int r = 0; r < 32; r++) {
    int t = t_begin + r * 2 + half;
    const unsigned short* kvrow = kv + (size_t)(b * N_ + t) * 512;
    u16x8 kb = *(const u16x8*)(kvrow + sub * 8);
    float kf[8];
#pragma unroll
    for (int j = 0; j < 8; j++) kf[j] = b2f(kb[j]);
    float d[8];
#pragma unroll
    for (int s = 0; s < 8; s++) {
      float a = 0.f;
#pragma unroll
      for (int j = 0; j < 8; j++) a += qr[s][j] * kf[j];
      d[s] = a;
    }
#pragma unroll
    for (int m = 1; m < 32; m <<= 1)
#pragma unroll
      for (int s = 0; s < 8; s++) d[s] += __shfl_xor(d[s], m);
    // softmax over slots (+EPS)
    float mx = d[0];
#pragma unroll
    for (int s = 1; s < 8; s++) mx = fmaxf(mx, d[s]);
    float e[8], sum = 0.f;
#pragma unroll
    for (int s = 0; s < 8; s++) { e[s] = __expf(d[s] - mx); sum += e[s]; }
    float inv = 1.f / sum;
#pragma unroll
    for (int s = 0; s < 8; s++) e[s] = e[s] * inv + 1e-8f;
    u16x8 vb = *(const u16x8*)(kvrow + 256 + sub * 8);
    float vf[8];
#pragma unroll
    for (int j = 0; j < 8; j++) vf[j] = b2f(vb[j]);
#pragma unroll
    for (int s = 0; s < 8; s++) {
#pragma unroll
      for (int j = 0; j < 8; j++) acc[s][j] += e[s] * vf[j];
      den[s] += e[s];
    }
  }
  // merge the two halves (same column set, different t's)
#pragma unroll
  for (int s = 0; s < 8; s++) {
    den[s] += __shfl_xor(den[s], 32);
#pragma unroll
    for (int j = 0; j < 8; j++) acc[s][j] += __shfl_xor(acc[s][j], 32);
  }
  if (half == 0) {
    float* np = nump + (((size_t)b * 16 + chunk) * 4 + wave) * (S_ * 256);
#pragma unroll
    for (int s = 0; s < 8; s++) {
      float4 v0; v0.x = acc[s][0]; v0.y = acc[s][1]; v0.z = acc[s][2]; v0.w = acc[s][3];
      float4 v1; v1.x = acc[s][4]; v1.y = acc[s][5]; v1.z = acc[s][6]; v1.w = acc[s][7];
      *(float4*)(np + s * 256 + sub * 8) = v0;
      *(float4*)(np + s * 256 + sub * 8 + 4) = v1;
    }
    if (sub == 0) {
      float* dp = denp + (((size_t)b * 16 + chunk) * 4 + wave) * S_;
#pragma unroll
      for (int s = 0; s < 8; s++) dp[s] = den[s];
    }
  }
}

// ---------------------------------------------------------------------------
// Slot update: updates=num/den, GRU, residual pre-LN MLP. block per (b,s) row.
// ---------------------------------------------------------------------------
__global__ __launch_bounds__(256) void k_slot(const float* __restrict__ slots_prev,
                                              const float* __restrict__ nump,
                                              const float* __restrict__ denp,
                                              const float* __restrict__ wihT,  // [256][768]
                                              const float* __restrict__ whhT,  // [256][768]
                                              const float* __restrict__ bih,
                                              const float* __restrict__ bhh,
                                              const float* __restrict__ lng,
                                              const float* __restrict__ lnb,
                                              const float* __restrict__ w1,    // [256][1024]
                                              const float* __restrict__ b1,
                                              const float* __restrict__ w2,    // [1024][256]
                                              const float* __restrict__ b2,
                                              float* __restrict__ slots_out) {
  __shared__ float upd[256], sp[256], lnv[256], m1s[1024];
  __shared__ float red[8];
  int row = blockIdx.x;            // b*8 + s
  int b = row >> 3, s = row & 7;
  int tid = threadIdx.x;
  // reduce attention partials
  float u = 0.f;
  for (int c = 0; c < 16; c++)
#pragma unroll
    for (int w = 0; w < 4; w++)
      u += nump[((((size_t)b * 16 + c) * 4 + w) * 8 + s) * 256 + tid];
  float dn = 0.f;
  for (int c = 0; c < 16; c++)
#pragma unroll
    for (int w = 0; w < 4; w++)
      dn += denp[(((size_t)b * 16 + c) * 4 + w) * 8 + s];
  u /= dn;
  upd[tid] = u;
  float spv = slots_prev[row * 256 + tid];
  sp[tid] = spv;
  __syncthreads();
  // gi/gh: each thread outputs gates r(tid), z(tid), n(tid)
  float gi0 = bih[tid], gi1 = bih[tid + 256], gi2 = bih[tid + 512];
  float gh0 = bhh[tid], gh1 = bhh[tid + 256], gh2 = bhh[tid + 512];
  for (int k = 0; k < 256; k++) {
    float uk = upd[k], sk = sp[k];
    const float* wi = wihT + k * 768;
    const float* wh = whhT + k * 768;
    gi0 += uk * wi[tid]; gi1 += uk * wi[tid + 256]; gi2 += uk * wi[tid + 512];
    gh0 += sk * wh[tid]; gh1 += sk * wh[tid + 256]; gh2 += sk * wh[tid + 512];
  }
  float rg = 1.f / (1.f + __expf(-(gi0 + gh0)));
  float zg = 1.f / (1.f + __expf(-(gi1 + gh1)));
  float ng = tanhf(gi2 + rg * gh2);
  float h = (1.f - zg) * ng + zg * spv;
  // LN(h)
  float ss = h, sq = h * h;
#pragma unroll
  for (int m = 1; m < 64; m <<= 1) { ss += __shfl_xor(ss, m); sq += __shfl_xor(sq, m); }
  if ((tid & 63) == 0) { red[tid >> 6] = ss; red[4 + (tid >> 6)] = sq; }
  __syncthreads();
  ss = red[0] + red[1] + red[2] + red[3];
  sq = red[4] + red[5] + red[6] + red[7];
  float mean = ss * (1.f / 256.f);
  float rstd = rsqrtf(sq * (1.f / 256.f) - mean * mean + 1e-5f);
  lnv[tid] = (h - mean) * rstd * lng[tid] + lnb[tid];
  __syncthreads();
  // m1 = relu(ln @ w1 + b1): 4 outputs per thread
  float a0 = b1[tid], a1 = b1[tid + 256], a2 = b1[tid + 512], a3 = b1[tid + 768];
  for (int k = 0; k < 256; k++) {
    float lv = lnv[k];
    const float* wr = w1 + k * 1024;
    a0 += lv * wr[tid]; a1 += lv * wr[tid + 256]; a2 += lv * wr[tid + 512]; a3 += lv * wr[tid + 768];
  }
  m1s[tid] = fmaxf(a0, 0.f); m1s[tid + 256] = fmaxf(a1, 0.f);
  m1s[tid + 512] = fmaxf(a2, 0.f); m1s[tid + 768] = fmaxf(a3, 0.f);
  __syncthreads();
  float o = b2[tid];
  for (int k = 0; k < 1024; k++) o += m1s[k] * w2[k * 256 + tid];
  slots_out[row * 256 + tid] = h + o;
}

// ---------------------------------------------------------------------------
extern "C" void kernel_launch(void* const* d_in, const int* in_sizes, int n_in,
                              void* d_out, int out_size, void* d_ws, size_t ws_size,
                              hipStream_t stream) {
  const float* inputs     = (const float*)d_in[0];
  const float* slots_init = (const float*)d_in[1];
  const float* ln1g = (const float*)d_in[2];
  const float* ln1b = (const float*)d_in[3];
  const float* w1   = (const float*)d_in[4];
  const float* b1   = (const float*)d_in[5];
  const float* w2   = (const float*)d_in[6];
  const float* b2   = (const float*)d_in[7];
  const float* ln2g = (const float*)d_in[8];
  const float* ln2b = (const float*)d_in[9];
  const float* wq   = (const float*)d_in[10];
  const float* wk   = (const float*)d_in[11];
  const float* wv   = (const float*)d_in[12];
  const float* normg = (const float*)d_in[13];
  const float* normb = (const float*)d_in[14];
  const float* gwih = (const float*)d_in[15];
  const float* gwhh = (const float*)d_in[16];
  const float* gbih = (const float*)d_in[17];
  const float* gbhh = (const float*)d_in[18];
  const float* mlng = (const float*)d_in[19];
  const float* mlnb = (const float*)d_in[20];
  const float* mw1  = (const float*)d_in[21];
  const float* mb1  = (const float*)d_in[22];
  const float* mw2  = (const float*)d_in[23];
  const float* mb2  = (const float*)d_in[24];

  char* ws = (char*)d_ws;
  size_t off = 0;
  auto take = [&](size_t bytes) -> char* {
    char* p = ws + off;
    off += (bytes + 255) & ~(size_t)255;
    return p;
  };
  unsigned short* R0   = (unsigned short*)take((size_t)131072 * 768 * 2);  // h0 bf16; later kv
  unsigned short* R1   = (unsigned short*)take((size_t)131072 * 768 * 2);  // h1 bf16; later feats
  unsigned short* h2bf = (unsigned short*)take((size_t)131072 * 256 * 2);
  unsigned short* w1T  = (unsigned short*)take(768 * 768 * 2);
  unsigned short* w2T  = (unsigned short*)take(256 * 768 * 2);
  unsigned short* wkvT = (unsigned short*)take(512 * 256 * 2);
  float* wqT   = (float*)take(65536 * 4);
  float* wihT  = (float*)take(196608 * 4);
  float* whhT  = (float*)take(196608 * 4);
  float* slotsA = (float*)take(65536 * 4);
  float* slotsB = (float*)take(65536 * 4);
  float* qbuf   = (float*)take(65536 * 4);
  float* nump   = (float*)take((size_t)4194304 * 4);
  float* denp   = (float*)take(16384 * 4);

  unsigned short* h0bf  = R0;
  unsigned short* kv    = R0;   // reuses h0 space (dead after GEMM1)
  unsigned short* h1bf  = R1;
  unsigned short* feats = R1;   // reuses h1 space (dead after GEMM2)

  // weight prep
  k_prep_w1t<<<2304, 256, 0, stream>>>(w1, w1T);
  k_prep_w2t<<<768, 256, 0, stream>>>(w2, w2T);
  k_prep_wkv<<<512, 256, 0, stream>>>(wk, wv, wkvT);
  k_prep_wqt<<<256, 256, 0, stream>>>(wq, wqT);
  k_prep_grut<<<768, 256, 0, stream>>>(gwih, gwhh, wihT, whhT);
  k_init_slots<<<256, 256, 0, stream>>>(slots_init, slotsA);

  // feature path
  k_h0<<<32768, 256, 0, stream>>>(inputs, ln1g, ln1b, h0bf);
  k_gemm<0><<<dim3(1024, 6), 256, 0, stream>>>(h0bf, w1T, b1, h1bf, 131072, 768, 768);
  k_gemm<1><<<dim3(1024, 2), 256, 0, stream>>>(h1bf, w2T, b2, h2bf, 131072, 256, 768);
  k_ln2<<<32768, 256, 0, stream>>>(h2bf, ln2g, ln2b, feats);
  k_gemm<2><<<dim3(1024, 4), 256, 0, stream>>>(feats, wkvT, nullptr, kv, 131072, 512, 256);

  // slot iterations (straight-through on last iter is forward-identity)
  const float* sin_[3] = {slotsA, slotsB, slotsA};
  float* sout_[3] = {slotsB, slotsA, (float*)d_out};
  for (int it = 0; it < 3; ++it) {
    k_q<<<256, 256, 0, stream>>>(sin_[it], normg, normb, wqT, qbuf);
    k_attn<<<dim3(16, 32), 256, 0, stream>>>(qbuf, kv, nump, denp);
    k_slot<<<256, 256, 0, stream>>>(sin_[it], nump, denp, wihT, whhT, gbih, gbhh,
                                    mlng, mlnb, mw1, mb1, mw2, mb2, sout_[it]);
  }
}

// Round 3
// 1394.511 us; speedup vs baseline: 1.1525x; 1.1525x over previous
//
#include <hip/hip_runtime.h>

// ---------------------------------------------------------------------------
// Slot Attention forward, MI355X (gfx950).
// B=32, N=4096, DIN=768, D=256, S=8, ITERS=3, SCALE=1/16, EPS=1e-8
// Big GEMMs: bf16 MFMA 16x16x32 + global_load_lds(16B) staging (m97 pattern).
// Slot-side: fp32 accumulate, fp16 dot2 weights.
// ---------------------------------------------------------------------------

typedef __bf16 bf16x8 __attribute__((ext_vector_type(8)));
typedef float f32x4 __attribute__((ext_vector_type(4)));
typedef unsigned short u16x8 __attribute__((ext_vector_type(8)));
typedef unsigned short u16x4 __attribute__((ext_vector_type(4)));
typedef __fp16 h2 __attribute__((ext_vector_type(2)));   // matches V2h builtin type

#define B_ 32
#define N_ 4096
#define S_ 8
#define SCALE_ 0.0625f

__device__ __forceinline__ unsigned short f2b(float f) {
  unsigned u = __float_as_uint(f);
  u = (u + 0x7fffu + ((u >> 16) & 1u)) >> 16;
  return (unsigned short)u;
}
__device__ __forceinline__ float b2f(unsigned short h) {
  return __uint_as_float(((unsigned)h) << 16);
}
__device__ __forceinline__ f32x4 mfma16(bf16x8 a, bf16x8 b, f32x4 c) {
  return __builtin_amdgcn_mfma_f32_16x16x32_bf16(a, b, c, 0, 0, 0);
}
// async global->LDS, 16 B per lane; lds dst = wave-uniform base + lane*16
__device__ __forceinline__ void gload16(const unsigned short* g, unsigned short* l) {
  __builtin_amdgcn_global_load_lds(
      (const __attribute__((address_space(1))) unsigned int*)(const void*)g,
      (__attribute__((address_space(3))) unsigned int*)(void*)l, 16, 0, 0);
}
__device__ __forceinline__ h2 pk(float x, float y) {
  return __builtin_amdgcn_cvt_pkrtz(x, y);
}
__device__ __forceinline__ float dot2(h2 a, h2 b, float c) {
  return __builtin_amdgcn_fdot2(a, b, c, false);
}

// ---------------------------------------------------------------------------
// Weight prep kernels
// ---------------------------------------------------------------------------
__global__ void k_prep_w1t(const float* __restrict__ w, unsigned short* __restrict__ o) {
  int idx = blockIdx.x * 256 + threadIdx.x;            // < 768*768
  int n = idx / 768, k = idx - n * 768;
  o[idx] = f2b(w[k * 768 + n]);                        // [n][k] bf16
}
__global__ void k_prep_w2t(const float* __restrict__ w, unsigned short* __restrict__ o) {
  int idx = blockIdx.x * 256 + threadIdx.x;            // < 256*768
  int n = idx / 768, k = idx - n * 768;
  o[idx] = f2b(w[k * 256 + n]);                        // [n=256][k=768]
}
__global__ void k_prep_wkv(const float* __restrict__ wk, const float* __restrict__ wv,
                           unsigned short* __restrict__ o) {
  int idx = blockIdx.x * 256 + threadIdx.x;            // < 512*256
  o[idx] = f2b(idx < 65536 ? wk[idx] : wv[idx - 65536]);
}
// wq [n][k] -> packed [kp][n] h2 (pairs along k)
__global__ void k_prep_wqp(const float* __restrict__ w, h2* __restrict__ o) {
  int idx = blockIdx.x * 256 + threadIdx.x;            // < 128*256
  int kp = idx >> 8, n = idx & 255;
  o[idx] = pk(w[n * 256 + 2 * kp], w[n * 256 + 2 * kp + 1]);
}
// gru W [768][256] -> packed [kp=128][768]
__global__ void k_prep_grup(const float* __restrict__ wih, const float* __restrict__ whh,
                            h2* __restrict__ oih, h2* __restrict__ ohh) {
  int idx = blockIdx.x * 256 + threadIdx.x;            // < 128*768
  int kp = idx / 768, n = idx - kp * 768;
  oih[idx] = pk(wih[n * 256 + 2 * kp], wih[n * 256 + 2 * kp + 1]);
  ohh[idx] = pk(whh[n * 256 + 2 * kp], whh[n * 256 + 2 * kp + 1]);
}
// mlp w1 [256][1024] -> [kp=128][1024]; w2 [1024][256] -> [kp=512][256]
__global__ void k_prep_w1p(const float* __restrict__ w, h2* __restrict__ o) {
  int idx = blockIdx.x * 256 + threadIdx.x;            // < 128*1024
  int kp = idx >> 10, n = idx & 1023;
  o[idx] = pk(w[2 * kp * 1024 + n], w[(2 * kp + 1) * 1024 + n]);
}
__global__ void k_prep_w2p(const float* __restrict__ w, h2* __restrict__ o) {
  int idx = blockIdx.x * 256 + threadIdx.x;            // < 512*256
  int kp = idx >> 8, n = idx & 255;
  o[idx] = pk(w[2 * kp * 256 + n], w[(2 * kp + 1) * 256 + n]);
}
__global__ void k_init_slots(const float* __restrict__ si, float* __restrict__ s) {
  int idx = blockIdx.x * 256 + threadIdx.x;            // < 65536
  s[idx] = si[idx & 2047];
}

// ---------------------------------------------------------------------------
// LN(768) + bf16 cast
// ---------------------------------------------------------------------------
__global__ __launch_bounds__(256) void k_h0(const float* __restrict__ x,
                                            const float* __restrict__ g,
                                            const float* __restrict__ b,
                                            unsigned short* __restrict__ out) {
  int row = blockIdx.x * 4 + (threadIdx.x >> 6);
  int lane = threadIdx.x & 63;
  const float* xr = x + (size_t)row * 768;
  float4 v[3];
  float s = 0.f, sq = 0.f;
#pragma unroll
  for (int q = 0; q < 3; q++) {
    v[q] = *(const float4*)(xr + q * 256 + lane * 4);
    s  += v[q].x + v[q].y + v[q].z + v[q].w;
    sq += v[q].x * v[q].x + v[q].y * v[q].y + v[q].z * v[q].z + v[q].w * v[q].w;
  }
#pragma unroll
  for (int m = 1; m < 64; m <<= 1) { s += __shfl_xor(s, m); sq += __shfl_xor(sq, m); }
  float mean = s * (1.f / 768.f);
  float rstd = rsqrtf(sq * (1.f / 768.f) - mean * mean + 1e-5f);
  unsigned short* orow = out + (size_t)row * 768;
#pragma unroll
  for (int q = 0; q < 3; q++) {
    float4 gv = *(const float4*)(g + q * 256 + lane * 4);
    float4 bv = *(const float4*)(b + q * 256 + lane * 4);
    u16x4 o;
    o[0] = f2b((v[q].x - mean) * rstd * gv.x + bv.x);
    o[1] = f2b((v[q].y - mean) * rstd * gv.y + bv.y);
    o[2] = f2b((v[q].z - mean) * rstd * gv.z + bv.z);
    o[3] = f2b((v[q].w - mean) * rstd * gv.w + bv.w);
    *(u16x4*)(orow + q * 256 + lane * 4) = o;
  }
}

// LN(256) bf16 -> bf16
__global__ __launch_bounds__(256) void k_ln2(const unsigned short* __restrict__ h2i,
                                             const float* __restrict__ g,
                                             const float* __restrict__ b,
                                             unsigned short* __restrict__ out) {
  int row = blockIdx.x * 4 + (threadIdx.x >> 6);
  int lane = threadIdx.x & 63;
  u16x4 hv = *(const u16x4*)(h2i + (size_t)row * 256 + lane * 4);
  float x0 = b2f(hv[0]), x1 = b2f(hv[1]), x2 = b2f(hv[2]), x3 = b2f(hv[3]);
  float s = x0 + x1 + x2 + x3;
  float sq = x0 * x0 + x1 * x1 + x2 * x2 + x3 * x3;
#pragma unroll
  for (int m = 1; m < 64; m <<= 1) { s += __shfl_xor(s, m); sq += __shfl_xor(sq, m); }
  float mean = s * (1.f / 256.f);
  float rstd = rsqrtf(sq * (1.f / 256.f) - mean * mean + 1e-5f);
  float4 gv = *(const float4*)(g + lane * 4);
  float4 bv = *(const float4*)(b + lane * 4);
  u16x4 o;
  o[0] = f2b((x0 - mean) * rstd * gv.x + bv.x);
  o[1] = f2b((x1 - mean) * rstd * gv.y + bv.y);
  o[2] = f2b((x2 - mean) * rstd * gv.z + bv.z);
  o[3] = f2b((x3 - mean) * rstd * gv.w + bv.w);
  *(u16x4*)(out + (size_t)row * 256 + lane * 4) = o;
}

// ---------------------------------------------------------------------------
// bf16 MFMA GEMM, m97-style: 128x128 tile, BK=32, unpadded LDS (stride 32),
// global_load_lds width-16 staging. Linearized grid, column-fastest for A reuse.
// ---------------------------------------------------------------------------
template <int MODE>  // 0: relu(x+bias)  1: x+bias  2: x
__global__ __launch_bounds__(256) void k_gemm(const unsigned short* __restrict__ A,
                                              const unsigned short* __restrict__ Bm,
                                              const float* __restrict__ bias,
                                              unsigned short* __restrict__ C,
                                              int M, int N, int K, int nbn) {
  __shared__ __attribute__((aligned(16))) unsigned short lA[128 * 32];
  __shared__ __attribute__((aligned(16))) unsigned short lB[128 * 32];
  const int tid = threadIdx.x;
  const int lane = tid & 63, wave = tid >> 6;
  const int bid = blockIdx.x;
  const int bm = bid / nbn, bn = bid - bm * nbn;
  const int m0 = bm * 128, n0 = bn * 128;
  const int wm = (wave >> 1) * 64, wn = (wave & 1) * 64;
  // staging: wave w covers rows [w*16, w*16+16) (+64 for second call);
  // lane covers row lane>>2, 8-element chunk (lane&3)*8
  const int srow = lane >> 2, soff = (lane & 3) * 8;
  const unsigned short* gA0 = A + (size_t)(m0 + wave * 16 + srow) * K + soff;
  const unsigned short* gA1 = gA0 + (size_t)64 * K;
  const unsigned short* gB0 = Bm + (size_t)(n0 + wave * 16 + srow) * K + soff;
  const unsigned short* gB1 = gB0 + (size_t)64 * K;
  unsigned short* lA0 = &lA[(wave * 16) * 32];
  unsigned short* lA1 = &lA[(64 + wave * 16) * 32];
  unsigned short* lB0 = &lB[(wave * 16) * 32];
  unsigned short* lB1 = &lB[(64 + wave * 16) * 32];
  const int fr = lane & 15, fq = lane >> 4;

  f32x4 acc[4][4] = {};
  for (int kt = 0; kt < K; kt += 32) {
    __syncthreads();  // prev iter's LDS reads complete
    gload16(gA0 + kt, lA0);
    gload16(gA1 + kt, lA1);
    gload16(gB0 + kt, lB0);
    gload16(gB1 + kt, lB1);
    __syncthreads();  // drains vmcnt(0): staged tiles visible
    bf16x8 af[4], bfr[4];
#pragma unroll
    for (int i = 0; i < 4; i++)
      af[i] = __builtin_bit_cast(bf16x8, *(const u16x8*)&lA[(wm + i * 16 + fr) * 32 + fq * 8]);
#pragma unroll
    for (int j = 0; j < 4; j++)
      bfr[j] = __builtin_bit_cast(bf16x8, *(const u16x8*)&lB[(wn + j * 16 + fr) * 32 + fq * 8]);
#pragma unroll
    for (int i = 0; i < 4; i++)
#pragma unroll
      for (int j = 0; j < 4; j++)
        acc[i][j] = mfma16(af[i], bfr[j], acc[i][j]);
  }
#pragma unroll
  for (int i = 0; i < 4; i++)
#pragma unroll
    for (int j = 0; j < 4; j++) {
      int col = n0 + wn + j * 16 + fr;
      float bv = (MODE == 2) ? 0.f : bias[col];
#pragma unroll
      for (int r = 0; r < 4; r++) {
        int row = m0 + wm + i * 16 + fq * 4 + r;
        float v = acc[i][j][r] + bv;
        if (MODE == 0) v = fmaxf(v, 0.f);
        C[(size_t)row * N + col] = f2b(v);
      }
    }
}

// ---------------------------------------------------------------------------
// q = LN(slots) @ wq^T * SCALE. one block per (b,s) row; fp16 dot2 weights.
// ---------------------------------------------------------------------------
__global__ __launch_bounds__(256) void k_q(const float* __restrict__ slots,
                                           const float* __restrict__ ng,
                                           const float* __restrict__ nb,
                                           const h2* __restrict__ wqp,  // [kp=128][256]
                                           float* __restrict__ qout) {
  __shared__ float ln[256];
  __shared__ float red[8];
  int row = blockIdx.x, tid = threadIdx.x;
  float x = slots[row * 256 + tid];
  float s = x, sq = x * x;
#pragma unroll
  for (int m = 1; m < 64; m <<= 1) { s += __shfl_xor(s, m); sq += __shfl_xor(sq, m); }
  if ((tid & 63) == 0) { red[tid >> 6] = s; red[4 + (tid >> 6)] = sq; }
  __syncthreads();
  s = red[0] + red[1] + red[2] + red[3];
  sq = red[4] + red[5] + red[6] + red[7];
  float mean = s * (1.f / 256.f);
  float rstd = rsqrtf(sq * (1.f / 256.f) - mean * mean + 1e-5f);
  ln[tid] = (x - mean) * rstd * ng[tid] + nb[tid];
  __syncthreads();
  float acc = 0.f;
#pragma unroll 4
  for (int kp = 0; kp < 128; kp++) {
    float2 lf = *(const float2*)&ln[2 * kp];
    acc = dot2(wqp[kp * 256 + tid], pk(lf.x, lf.y), acc);
  }
  qout[row * 256 + tid] = acc * SCALE_;
}

// ---------------------------------------------------------------------------
// Attention with in-block cross-wave reduction: nump [B][16][S][256]
// ---------------------------------------------------------------------------
__global__ __launch_bounds__(256) void k_attn(const float* __restrict__ q,
                                              const unsigned short* __restrict__ kv,
                                              float* __restrict__ nump,
                                              float* __restrict__ denp) {
  __shared__ float racc[4][8][256];
  __shared__ float rden[4][8];
  int b = blockIdx.y, chunk = blockIdx.x;
  int tid = threadIdx.x, lane = tid & 63, wave = tid >> 6;
  int sub = lane & 31, half = lane >> 5;
  const float* qb = q + b * (S_ * 256);
  float qr[8][8];
#pragma unroll
  for (int s = 0; s < 8; s++) {
    float4 t0 = *(const float4*)(qb + s * 256 + sub * 8);
    float4 t1 = *(const float4*)(qb + s * 256 + sub * 8 + 4);
    qr[s][0] = t0.x; qr[s][1] = t0.y; qr[s][2] = t0.z; qr[s][3] = t0.w;
    qr[s][4] = t1.x; qr[s][5] = t1.y; qr[s][6] = t1.z; qr[s][7] = t1.w;
  }
  float acc[8][8] = {};
  float den[8] = {};
  int t_begin = chunk * 256 + wave * 64;
  for (int r = 0; r < 32; r++) {
    int t = t_begin + r * 2 + half;
    const unsigned short* kvrow = kv + (size_t)(b * N_ + t) * 512;
    u16x8 kb = *(const u16x8*)(kvrow + sub * 8);
    float kf[8];
#pragma unroll
    for (int j = 0; j < 8; j++) kf[j] = b2f(kb[j]);
    float d[8];
#pragma unroll
    for (int s = 0; s < 8; s++) {
      float a = 0.f;
#pragma unroll
      for (int j = 0; j < 8; j++) a += qr[s][j] * kf[j];
      d[s] = a;
    }
#pragma unroll
    for (int m = 1; m < 32; m <<= 1)
#pragma unroll
      for (int s = 0; s < 8; s++) d[s] += __shfl_xor(d[s], m);
    float mx = d[0];
#pragma unroll
    for (int s = 1; s < 8; s++) mx = fmaxf(mx, d[s]);
    float e[8], sum = 0.f;
#pragma unroll
    for (int s = 0; s < 8; s++) { e[s] = __expf(d[s] - mx); sum += e[s]; }
    float inv = 1.f / sum;
#pragma unroll
    for (int s = 0; s < 8; s++) e[s] = e[s] * inv + 1e-8f;
    u16x8 vb = *(const u16x8*)(kvrow + 256 + sub * 8);
    float vf[8];
#pragma unroll
    for (int j = 0; j < 8; j++) vf[j] = b2f(vb[j]);
#pragma unroll
    for (int s = 0; s < 8; s++) {
#pragma unroll
      for (int j = 0; j < 8; j++) acc[s][j] += e[s] * vf[j];
      den[s] += e[s];
    }
  }
#pragma unroll
  for (int s = 0; s < 8; s++) {
    den[s] += __shfl_xor(den[s], 32);
#pragma unroll
    for (int j = 0; j < 8; j++) acc[s][j] += __shfl_xor(acc[s][j], 32);
  }
  if (half == 0) {
#pragma unroll
    for (int s = 0; s < 8; s++)
#pragma unroll
      for (int j = 0; j < 8; j++) racc[wave][s][sub * 8 + j] = acc[s][j];
    if (sub == 0)
#pragma unroll
      for (int s = 0; s < 8; s++) rden[wave][s] = den[s];
  }
  __syncthreads();
  int s = tid >> 5, c0 = (tid & 31) * 8;
  float* np = nump + (((size_t)b * 16 + chunk) * 8 + s) * 256 + c0;
  float4 v0, v1;
  v0.x = racc[0][s][c0 + 0] + racc[1][s][c0 + 0] + racc[2][s][c0 + 0] + racc[3][s][c0 + 0];
  v0.y = racc[0][s][c0 + 1] + racc[1][s][c0 + 1] + racc[2][s][c0 + 1] + racc[3][s][c0 + 1];
  v0.z = racc[0][s][c0 + 2] + racc[1][s][c0 + 2] + racc[2][s][c0 + 2] + racc[3][s][c0 + 2];
  v0.w = racc[0][s][c0 + 3] + racc[1][s][c0 + 3] + racc[2][s][c0 + 3] + racc[3][s][c0 + 3];
  v1.x = racc[0][s][c0 + 4] + racc[1][s][c0 + 4] + racc[2][s][c0 + 4] + racc[3][s][c0 + 4];
  v1.y = racc[0][s][c0 + 5] + racc[1][s][c0 + 5] + racc[2][s][c0 + 5] + racc[3][s][c0 + 5];
  v1.z = racc[0][s][c0 + 6] + racc[1][s][c0 + 6] + racc[2][s][c0 + 6] + racc[3][s][c0 + 6];
  v1.w = racc[0][s][c0 + 7] + racc[1][s][c0 + 7] + racc[2][s][c0 + 7] + racc[3][s][c0 + 7];
  *(float4*)np = v0;
  *(float4*)(np + 4) = v1;
  if (tid < 8)
    denp[((size_t)b * 16 + chunk) * 8 + tid] =
        rden[0][tid] + rden[1][tid] + rden[2][tid] + rden[3][tid];
}

// ---------------------------------------------------------------------------
// Slot update: updates=num/den, GRU, residual pre-LN MLP. fp16 dot2 weights.
// one block per (b,s) row, tid = feature n.
// ---------------------------------------------------------------------------
__global__ __launch_bounds__(256) void k_slot(const float* __restrict__ slots_prev,
                                              const float* __restrict__ nump,
                                              const float* __restrict__ denp,
                                              const h2* __restrict__ gihp,  // [128][768]
                                              const h2* __restrict__ ghhp,  // [128][768]
                                              const float* __restrict__ bih,
                                              const float* __restrict__ bhh,
                                              const float* __restrict__ lng,
                                              const float* __restrict__ lnb,
                                              const h2* __restrict__ w1p,   // [128][1024]
                                              const float* __restrict__ b1,
                                              const h2* __restrict__ w2p,   // [512][256]
                                              const float* __restrict__ b2,
                                              float* __restrict__ slots_out) {
  __shared__ float upd[256], sp[256], lnv[256], m1[1024];
  __shared__ h2 m1s2[512];
  __shared__ float red[8];
  int row = blockIdx.x;            // b*8 + s
  int b = row >> 3, s = row & 7;
  int tid = threadIdx.x;
  float u = 0.f;
#pragma unroll
  for (int c = 0; c < 16; c++)
    u += nump[(((size_t)b * 16 + c) * 8 + s) * 256 + tid];
  float dn = 0.f;
#pragma unroll
  for (int c = 0; c < 16; c++)
    dn += denp[((size_t)b * 16 + c) * 8 + s];
  u /= dn;
  upd[tid] = u;
  float spv = slots_prev[row * 256 + tid];
  sp[tid] = spv;
  __syncthreads();
  float gi0 = bih[tid], gi1 = bih[tid + 256], gi2 = bih[tid + 512];
  float gh0 = bhh[tid], gh1 = bhh[tid + 256], gh2 = bhh[tid + 512];
#pragma unroll 4
  for (int kp = 0; kp < 128; kp++) {
    float2 uf = *(const float2*)&upd[2 * kp];
    float2 sf = *(const float2*)&sp[2 * kp];
    h2 u2 = pk(uf.x, uf.y), s2 = pk(sf.x, sf.y);
    const h2* wi = gihp + kp * 768;
    const h2* wh = ghhp + kp * 768;
    gi0 = dot2(wi[tid], u2, gi0);
    gi1 = dot2(wi[tid + 256], u2, gi1);
    gi2 = dot2(wi[tid + 512], u2, gi2);
    gh0 = dot2(wh[tid], s2, gh0);
    gh1 = dot2(wh[tid + 256], s2, gh1);
    gh2 = dot2(wh[tid + 512], s2, gh2);
  }
  float rg = 1.f / (1.f + __expf(-(gi0 + gh0)));
  float zg = 1.f / (1.f + __expf(-(gi1 + gh1)));
  float ng = tanhf(gi2 + rg * gh2);
  float h = (1.f - zg) * ng + zg * spv;
  // LN(h)
  float ss = h, sq = h * h;
#pragma unroll
  for (int m = 1; m < 64; m <<= 1) { ss += __shfl_xor(ss, m); sq += __shfl_xor(sq, m); }
  if ((tid & 63) == 0) { red[tid >> 6] = ss; red[4 + (tid >> 6)] = sq; }
  __syncthreads();
  ss = red[0] + red[1] + red[2] + red[3];
  sq = red[4] + red[5] + red[6] + red[7];
  float mean = ss * (1.f / 256.f);
  float rstd = rsqrtf(sq * (1.f / 256.f) - mean * mean + 1e-5f);
  lnv[tid] = (h - mean) * rstd * lng[tid] + lnb[tid];
  __syncthreads();
  float a0 = b1[tid], a1 = b1[tid + 256], a2 = b1[tid + 512], a3 = b1[tid + 768];
#pragma unroll 4
  for (int kp = 0; kp < 128; kp++) {
    float2 lf = *(const float2*)&lnv[2 * kp];
    h2 l2 = pk(lf.x, lf.y);
    const h2* wr = w1p + kp * 1024;
    a0 = dot2(wr[tid], l2, a0);
    a1 = dot2(wr[tid + 256], l2, a1);
    a2 = dot2(wr[tid + 512], l2, a2);
    a3 = dot2(wr[tid + 768], l2, a3);
  }
  m1[tid] = fmaxf(a0, 0.f); m1[tid + 256] = fmaxf(a1, 0.f);
  m1[tid + 512] = fmaxf(a2, 0.f); m1[tid + 768] = fmaxf(a3, 0.f);
  __syncthreads();
  m1s2[tid] = pk(m1[2 * tid], m1[2 * tid + 1]);
  if (tid < 256) m1s2[tid + 256] = pk(m1[512 + 2 * tid], m1[512 + 2 * tid + 1]);
  __syncthreads();
  float o = b2[tid];
#pragma unroll 8
  for (int kp = 0; kp < 512; kp++)
    o = dot2(w2p[kp * 256 + tid], m1s2[kp], o);
  slots_out[row * 256 + tid] = h + o;
}

// ---------------------------------------------------------------------------
extern "C" void kernel_launch(void* const* d_in, const int* in_sizes, int n_in,
                              void* d_out, int out_size, void* d_ws, size_t ws_size,
                              hipStream_t stream) {
  const float* inputs     = (const float*)d_in[0];
  const float* slots_init = (const float*)d_in[1];
  const float* ln1g = (const float*)d_in[2];
  const float* ln1b = (const float*)d_in[3];
  const float* w1   = (const float*)d_in[4];
  const float* b1   = (const float*)d_in[5];
  const float* w2   = (const float*)d_in[6];
  const float* b2   = (const float*)d_in[7];
  const float* ln2g = (const float*)d_in[8];
  const float* ln2b = (const float*)d_in[9];
  const float* wq   = (const float*)d_in[10];
  const float* wk   = (const float*)d_in[11];
  const float* wv   = (const float*)d_in[12];
  const float* normg = (const float*)d_in[13];
  const float* normb = (const float*)d_in[14];
  const float* gwih = (const float*)d_in[15];
  const float* gwhh = (const float*)d_in[16];
  const float* gbih = (const float*)d_in[17];
  const float* gbhh = (const float*)d_in[18];
  const float* mlng = (const float*)d_in[19];
  const float* mlnb = (const float*)d_in[20];
  const float* mw1  = (const float*)d_in[21];
  const float* mb1  = (const float*)d_in[22];
  const float* mw2  = (const float*)d_in[23];
  const float* mb2  = (const float*)d_in[24];

  char* ws = (char*)d_ws;
  size_t off = 0;
  auto take = [&](size_t bytes) -> char* {
    char* p = ws + off;
    off += (bytes + 255) & ~(size_t)255;
    return p;
  };
  // R0: h0 (201 MB) -> h2bf (67 MB) -> kv (134 MB)
  unsigned short* R0 = (unsigned short*)take((size_t)131072 * 768 * 2);
  // R1: h1 (201 MB) -> feats (67 MB)
  unsigned short* R1 = (unsigned short*)take((size_t)131072 * 768 * 2);
  unsigned short* w1T  = (unsigned short*)take(768 * 768 * 2);
  unsigned short* w2T  = (unsigned short*)take(256 * 768 * 2);
  unsigned short* wkvT = (unsigned short*)take(512 * 256 * 2);
  h2* wqp  = (h2*)take(128 * 256 * 4);
  h2* gihp = (h2*)take(128 * 768 * 4);
  h2* ghhp = (h2*)take(128 * 768 * 4);
  h2* w1p  = (h2*)take(128 * 1024 * 4);
  h2* w2p  = (h2*)take(512 * 256 * 4);
  float* slotsA = (float*)take(65536 * 4);
  float* slotsB = (float*)take(65536 * 4);
  float* qbuf   = (float*)take(65536 * 4);
  float* nump   = (float*)take((size_t)B_ * 16 * 8 * 256 * 4);  // 4 MB
  float* denp   = (float*)take(B_ * 16 * 8 * 4);

  unsigned short* h0bf  = R0;
  unsigned short* h1bf  = R1;
  unsigned short* h2bf  = R0;   // h0 dead after GEMM1
  unsigned short* feats = R1;   // h1 dead after GEMM2
  unsigned short* kv    = R0;   // h2bf dead after ln2

  k_prep_w1t<<<2304, 256, 0, stream>>>(w1, w1T);
  k_prep_w2t<<<768, 256, 0, stream>>>(w2, w2T);
  k_prep_wkv<<<512, 256, 0, stream>>>(wk, wv, wkvT);
  k_prep_wqp<<<128, 256, 0, stream>>>(wq, wqp);
  k_prep_grup<<<384, 256, 0, stream>>>(gwih, gwhh, gihp, ghhp);
  k_prep_w1p<<<512, 256, 0, stream>>>(mw1, w1p);
  k_prep_w2p<<<512, 256, 0, stream>>>(mw2, w2p);
  k_init_slots<<<256, 256, 0, stream>>>(slots_init, slotsA);

  k_h0<<<32768, 256, 0, stream>>>(inputs, ln1g, ln1b, h0bf);
  k_gemm<0><<<1024 * 6, 256, 0, stream>>>(h0bf, w1T, b1, h1bf, 131072, 768, 768, 6);
  k_gemm<1><<<1024 * 2, 256, 0, stream>>>(h1bf, w2T, b2, h2bf, 131072, 256, 768, 2);
  k_ln2<<<32768, 256, 0, stream>>>(h2bf, ln2g, ln2b, feats);
  k_gemm<2><<<1024 * 4, 256, 0, stream>>>(feats, wkvT, nullptr, kv, 131072, 512, 256, 4);

  const float* sin_[3] = {slotsA, slotsB, slotsA};
  float* sout_[3] = {slotsB, slotsA, (float*)d_out};
  for (int it = 0; it < 3; ++it) {
    k_q<<<256, 256, 0, stream>>>(sin_[it], normg, normb, wqp, qbuf);
    k_attn<<<dim3(16, 32), 256, 0, stream>>>(qbuf, kv, nump, denp);
    k_slot<<<256, 256, 0, stream>>>(sin_[it], nump, denp, gihp, ghhp, gbih, gbhh,
                                    mlng, mlnb, w1p, mb1, w2p, mb2, sout_[it]);
  }
}